// Round 13
// baseline (300.734 us; speedup 1.0000x reference)
//
#include <hip/hip_runtime.h>
#include <math.h>

#define NN 50000
#define NE 800000
#define FIN 128
#define HID 64
#define HEADS 4
#define C1 256   // HEADS*HID
#define CLS 40
#define EPSF 1e-16f

typedef __attribute__((ext_vector_type(8))) short bf16x8;
typedef __attribute__((ext_vector_type(4))) float f32x4;
typedef __attribute__((ext_vector_type(2))) float f32x2;

__device__ __forceinline__ unsigned short f2bf(float f) {
    unsigned int u = __float_as_uint(f);
    unsigned int r = (u + 0x7fffu + ((u >> 16) & 1u)) >> 16;   // RNE
    return (unsigned short)r;
}
__device__ __forceinline__ float bflo(unsigned int u) { return __uint_as_float(u << 16); }
__device__ __forceinline__ float bfhi(unsigned int u) { return __uint_as_float(u & 0xffff0000u); }
__device__ __forceinline__ unsigned char f2fp8(float v) {
    int pk = __builtin_amdgcn_cvt_pk_fp8_f32(v, v, 0, false);
    return (unsigned char)(pk & 0xff);
}

// ---------------- counting sort of edges by dst ----------------

__global__ void k_zero(int* a, int n) {
    int i = blockIdx.x * 256 + threadIdx.x;
    if (i < n) a[i] = 0;
}

__global__ void k_hist(const int* __restrict__ ei, int* __restrict__ counts) {
    int i = blockIdx.x * 256 + threadIdx.x;
    if (i < NE) atomicAdd(&counts[ei[NE + i]], 1);
}

__global__ __launch_bounds__(1024) void k_scan1(const int* __restrict__ counts,
                                                int* __restrict__ offs,
                                                int* __restrict__ partials) {
    __shared__ int s[1024];
    int t = threadIdx.x;
    int g = blockIdx.x * 1024 + t;
    int v = (g < NN) ? counts[g] : 0;
    s[t] = v;
    __syncthreads();
    for (int d = 1; d < 1024; d <<= 1) {
        int x = (t >= d) ? s[t - d] : 0;
        __syncthreads();
        s[t] += x;
        __syncthreads();
    }
    if (g < NN) offs[g] = s[t] - v;             // block-local exclusive
    if (t == 1023) partials[blockIdx.x] = s[t]; // block total
}

__global__ void k_scan2(int* partials, int nb) {
    if (threadIdx.x == 0 && blockIdx.x == 0) {
        int run = 0;
        for (int b = 0; b < nb; b++) { int v = partials[b]; partials[b] = run; run += v; }
    }
}

__global__ void k_scan3(int* __restrict__ offs, const int* __restrict__ partials,
                        int* __restrict__ cursor) {
    int g = blockIdx.x * 256 + threadIdx.x;
    if (g < NN) {
        int o = offs[g] + partials[g >> 10];
        offs[g] = o;
        cursor[g] = o;
    }
}

// packed (src,dst) scatter: ONE 8B line-touch per edge instead of two 4B
// writes to separate arrays (halves random-write line traffic).
__global__ void k_scatter(const int* __restrict__ ei, int* __restrict__ cursor,
                          int2* __restrict__ sedge) {
    int i = blockIdx.x * 256 + threadIdx.x;
    if (i < NE) {
        int s = ei[i];
        int d = ei[NE + i];
        int p = atomicAdd(&cursor[d], 1);
        int2 e; e.x = s; e.y = d;
        sedge[p] = e;
    }
}

// ---------------- per-edge softmax weights + tail padding ----------------

__global__ __launch_bounds__(256) void k_ew1(int2* __restrict__ sedge,
                                             const float* __restrict__ as1,
                                             const float* __restrict__ ad1,
                                             float4* __restrict__ pw1) {
    int j = blockIdx.x * 256 + threadIdx.x;
    if (j < NE) {
        int2 e2 = sedge[j];
        float4 a = *(const float4*)(as1 + e2.x * 4);
        float4 bb = *(const float4*)(ad1 + e2.y * 4);
        float4 e = {a.x + bb.x, a.y + bb.y, a.z + bb.z, a.w + bb.w};
        e.x = e.x > 0.f ? e.x : 0.2f * e.x;
        e.y = e.y > 0.f ? e.y : 0.2f * e.y;
        e.z = e.z > 0.f ? e.z : 0.2f * e.z;
        e.w = e.w > 0.f ? e.w : 0.2f * e.w;
        float4 p = {__expf(e.x), __expf(e.y), __expf(e.z), __expf(e.w)};
        pw1[j] = p;
    } else {
        if (j < NE + 16) pw1[j] = (float4){0.f, 0.f, 0.f, 0.f};
        if (j < NE + 32) { int2 z; z.x = 0; z.y = 0; sedge[j] = z; }
    }
}

__global__ __launch_bounds__(256) void k_ew2(const int2* __restrict__ sedge,
                                             const float* __restrict__ as2,
                                             const float* __restrict__ ad2,
                                             float* __restrict__ pw2) {
    int j = blockIdx.x * 256 + threadIdx.x;
    if (j < NE) {
        int2 e2 = sedge[j];
        float e = as2[e2.x] + ad2[e2.y];
        e = e > 0.f ? e : 0.2f * e;
        pw2[j] = __expf(e);
    } else if (j < NE + 16) {
        pw2[j] = 0.f;
    }
}

// ---------------- W1/W2 -> bf16 MFMA B-fragment buffers (one-time) -------
__global__ __launch_bounds__(256) void k_wconv(const float* __restrict__ W1,
                                               const float* __restrict__ W2,
                                               unsigned short* __restrict__ wB1,
                                               unsigned short* __restrict__ wB2) {
    int t = blockIdx.x * 256 + threadIdx.x;
    if (t < 4096) {
        int tn = t >> 8;
        int kc = (t >> 6) & 3;
        int l = t & 63;
        int n = tn * 16 + (l & 15);
        int k0 = kc * 32 + (l >> 4) * 8;
        unsigned short* o = wB1 + (size_t)t * 8;
#pragma unroll
        for (int j = 0; j < 8; j++) o[j] = f2bf(W1[(size_t)(k0 + j) * C1 + n]);
    } else if (t < 4096 + 1536) {
        int u = t - 4096;
        int tn = u >> 9;
        int kc = (u >> 6) & 7;
        int l = u & 63;
        int n = tn * 16 + (l & 15);
        int k0 = kc * 32 + (l >> 4) * 8;
        unsigned short* o = wB2 + (size_t)u * 8;
#pragma unroll
        for (int j = 0; j < 8; j++)
            o[j] = (n < CLS) ? f2bf(W2[(size_t)(k0 + j) * CLS + n]) : (unsigned short)0;
    }
}

// ---------------- layer 1: bf16 MFMA GEMM + fused alpha dots -------------
__global__ __launch_bounds__(256) void k_gemm1(const float* __restrict__ x,
                                               const unsigned short* __restrict__ wB,
                                               const float* __restrict__ aws,
                                               const float* __restrict__ awd,
                                               unsigned char* __restrict__ h1f8,
                                               float* __restrict__ as1,
                                               float* __restrict__ ad1) {
    __shared__ uint4 Af[4][4][64];   // [mt][kc][lane], 16 KB
    int t = threadIdx.x;
    int m0 = blockIdx.x * 64;

#pragma unroll
    for (int i = 0; i < 8; i++) {
        int g = i * 256 + t;
        int row = g >> 5;
        int c4 = g & 31;
        int grow = m0 + row;
        if (grow >= NN) grow = NN - 1;
        float4 v = *(const float4*)(x + (size_t)grow * FIN + c4 * 4);
        uint2 pk;
        pk.x = (unsigned int)f2bf(v.x) | ((unsigned int)f2bf(v.y) << 16);
        pk.y = (unsigned int)f2bf(v.z) | ((unsigned int)f2bf(v.w) << 16);
        int kc = c4 >> 3;
        int rem = (c4 & 7) * 4;
        int q = rem >> 3;
        int hh = (rem >> 2) & 1;
        int l = q * 16 + (row & 15);
        int mt = row >> 4;
        ((uint2*)&Af[mt][kc][l])[hh] = pk;
    }
    __syncthreads();

    int l = t & 63;
    int wv = t >> 6;

    bf16x8 a[4];
#pragma unroll
    for (int kc = 0; kc < 4; kc++) a[kc] = *(const bf16x8*)&Af[wv][kc][l];

    f32x4 acc[16];
#pragma unroll
    for (int tn = 0; tn < 16; tn++) acc[tn] = (f32x4){0.f, 0.f, 0.f, 0.f};

    const bf16x8* wb = (const bf16x8*)wB + l;
#pragma unroll
    for (int tn = 0; tn < 16; tn++) {
        bf16x8 b0 = wb[(tn * 4 + 0) * 64];
        bf16x8 b1 = wb[(tn * 4 + 1) * 64];
        bf16x8 b2 = wb[(tn * 4 + 2) * 64];
        bf16x8 b3 = wb[(tn * 4 + 3) * 64];
        acc[tn] = __builtin_amdgcn_mfma_f32_16x16x32_bf16(a[0], b0, acc[tn], 0, 0, 0);
        acc[tn] = __builtin_amdgcn_mfma_f32_16x16x32_bf16(a[1], b1, acc[tn], 0, 0, 0);
        acc[tn] = __builtin_amdgcn_mfma_f32_16x16x32_bf16(a[2], b2, acc[tn], 0, 0, 0);
        acc[tn] = __builtin_amdgcn_mfma_f32_16x16x32_bf16(a[3], b3, acc[tn], 0, 0, 0);
    }

    int q = l >> 4;
    int c = l & 15;
    int row0 = m0 + wv * 16 + q * 4;
    float psum[4][4], pdsum[4][4];
#pragma unroll
    for (int h = 0; h < 4; h++)
#pragma unroll
        for (int r = 0; r < 4; r++) { psum[h][r] = 0.f; pdsum[h][r] = 0.f; }

#pragma unroll
    for (int tn = 0; tn < 16; tn++) {
        int col = tn * 16 + c;
        int h = tn >> 2;
        float wsv = aws[col];
        float wdv = awd[col];
#pragma unroll
        for (int r = 0; r < 4; r++) {
            float v = acc[tn][r];
            int row = row0 + r;
            if (row < NN) h1f8[(size_t)row * C1 + col] = f2fp8(v);
            psum[h][r] = fmaf(v, wsv, psum[h][r]);
            pdsum[h][r] = fmaf(v, wdv, pdsum[h][r]);
        }
    }
#pragma unroll
    for (int h = 0; h < 4; h++)
#pragma unroll
        for (int r = 0; r < 4; r++) {
            float ps = psum[h][r], pd = pdsum[h][r];
#pragma unroll
            for (int s = 1; s < 16; s <<= 1) {
                ps += __shfl_xor(ps, s);
                pd += __shfl_xor(pd, s);
            }
            int row = row0 + r;
            if (c == 0 && row < NN) {
                as1[row * 4 + h] = ps;
                ad1[row * 4 + h] = pd;
            }
        }
}

// ---------------- layer 1 aggregation (fp8 messages, 2 edges/slot) -------
__global__ __launch_bounds__(256) void k_agg1(const unsigned char* __restrict__ h1f8,
                                              const float* __restrict__ pw1,
                                              const int* __restrict__ offs,
                                              const int2* __restrict__ sedge,
                                              const float* __restrict__ b1,
                                              unsigned short* __restrict__ g1b) {
    int lane = threadIdx.x & 63;
    int half = lane >> 5;
    int hl = lane & 31;          // channel group: ch hl*8..+7
    int head = hl >> 3;
    int node = blockIdx.x * 4 + (threadIdx.x >> 6);
    int beg = offs[node];
    int end = (node + 1 < NN) ? offs[node + 1] : NE;
    float l = 0.f;
    float acc[8];
#pragma unroll
    for (int c = 0; c < 8; c++) acc[c] = 0.f;
    const uint2* hv = (const uint2*)h1f8;   // 32 uint2 per row

    if (beg < end) {
        int idx[4];
#pragma unroll
        for (int i = 0; i < 4; i++) idx[i] = sedge[beg + 2 * i + half].x;
        uint2 hbA[2];
        float pA[2];
#pragma unroll
        for (int i = 0; i < 2; i++) {
            hbA[i] = hv[(size_t)idx[i] * 32 + hl];
            int e = beg + 2 * i + half;
            float p = pw1[e * 4 + head];
            pA[i] = (e < end) ? p : 0.f;
        }
        for (int j = beg; j < end; j += 8) {
            int idxN[4];
#pragma unroll
            for (int i = 0; i < 4; i++) idxN[i] = sedge[j + 8 + 2 * i + half].x;
            uint2 hbB[2];
            float pB[2];
#pragma unroll
            for (int i = 0; i < 2; i++) {
                hbB[i] = hv[(size_t)idx[2 + i] * 32 + hl];
                int e = j + 4 + 2 * i + half;
                float p = pw1[e * 4 + head];
                pB[i] = (e < end) ? p : 0.f;
            }
#pragma unroll
            for (int i = 0; i < 2; i++) {
                float p = pA[i];
                f32x2 v0 = __builtin_amdgcn_cvt_pk_f32_fp8(hbA[i].x, false);
                f32x2 v1 = __builtin_amdgcn_cvt_pk_f32_fp8(hbA[i].x, true);
                f32x2 v2 = __builtin_amdgcn_cvt_pk_f32_fp8(hbA[i].y, false);
                f32x2 v3 = __builtin_amdgcn_cvt_pk_f32_fp8(hbA[i].y, true);
                l += p;
                acc[0] = fmaf(p, v0.x, acc[0]);
                acc[1] = fmaf(p, v0.y, acc[1]);
                acc[2] = fmaf(p, v1.x, acc[2]);
                acc[3] = fmaf(p, v1.y, acc[3]);
                acc[4] = fmaf(p, v2.x, acc[4]);
                acc[5] = fmaf(p, v2.y, acc[5]);
                acc[6] = fmaf(p, v3.x, acc[6]);
                acc[7] = fmaf(p, v3.y, acc[7]);
            }
#pragma unroll
            for (int i = 0; i < 2; i++) {
                hbA[i] = hv[(size_t)idxN[i] * 32 + hl];
                int e = j + 8 + 2 * i + half;
                float p = pw1[e * 4 + head];
                pA[i] = (e < end) ? p : 0.f;
            }
#pragma unroll
            for (int i = 0; i < 2; i++) {
                float p = pB[i];
                f32x2 v0 = __builtin_amdgcn_cvt_pk_f32_fp8(hbB[i].x, false);
                f32x2 v1 = __builtin_amdgcn_cvt_pk_f32_fp8(hbB[i].x, true);
                f32x2 v2 = __builtin_amdgcn_cvt_pk_f32_fp8(hbB[i].y, false);
                f32x2 v3 = __builtin_amdgcn_cvt_pk_f32_fp8(hbB[i].y, true);
                l += p;
                acc[0] = fmaf(p, v0.x, acc[0]);
                acc[1] = fmaf(p, v0.y, acc[1]);
                acc[2] = fmaf(p, v1.x, acc[2]);
                acc[3] = fmaf(p, v1.y, acc[3]);
                acc[4] = fmaf(p, v2.x, acc[4]);
                acc[5] = fmaf(p, v2.y, acc[5]);
                acc[6] = fmaf(p, v3.x, acc[6]);
                acc[7] = fmaf(p, v3.y, acc[7]);
            }
#pragma unroll
            for (int i = 0; i < 4; i++) idx[i] = idxN[i];
        }
    }
    l += __shfl_xor(l, 32);
#pragma unroll
    for (int c = 0; c < 8; c++) acc[c] += __shfl_xor(acc[c], 32);

    if (half == 0) {
        float inv = 1.f / (l + EPSF);
        const float4* b1v = (const float4*)b1;
        float4 b0 = b1v[hl * 2];
        float4 b1_ = b1v[hl * 2 + 1];
        float o[8];
        o[0] = fmaxf(fmaf(acc[0], inv, b0.x), 0.f);
        o[1] = fmaxf(fmaf(acc[1], inv, b0.y), 0.f);
        o[2] = fmaxf(fmaf(acc[2], inv, b0.z), 0.f);
        o[3] = fmaxf(fmaf(acc[3], inv, b0.w), 0.f);
        o[4] = fmaxf(fmaf(acc[4], inv, b1_.x), 0.f);
        o[5] = fmaxf(fmaf(acc[5], inv, b1_.y), 0.f);
        o[6] = fmaxf(fmaf(acc[6], inv, b1_.z), 0.f);
        o[7] = fmaxf(fmaf(acc[7], inv, b1_.w), 0.f);
        uint4 ob;
        ob.x = (unsigned int)f2bf(o[0]) | ((unsigned int)f2bf(o[1]) << 16);
        ob.y = (unsigned int)f2bf(o[2]) | ((unsigned int)f2bf(o[3]) << 16);
        ob.z = (unsigned int)f2bf(o[4]) | ((unsigned int)f2bf(o[5]) << 16);
        ob.w = (unsigned int)f2bf(o[6]) | ((unsigned int)f2bf(o[7]) << 16);
        ((uint4*)g1b)[(size_t)node * 32 + hl] = ob;
    }
}

// ---------------- layer 2: bf16 MFMA GEMM + fused alpha2 -----------------
__global__ __launch_bounds__(256) void k_gemm2(const unsigned short* __restrict__ g1b,
                                               const unsigned short* __restrict__ wB2,
                                               const float* __restrict__ aws,
                                               const float* __restrict__ awd,
                                               unsigned short* __restrict__ h2b,
                                               float* __restrict__ as2,
                                               float* __restrict__ ad2) {
    __shared__ uint4 Af[4][8][64];   // [mt][kc][lane], 32 KB
    int t = threadIdx.x;
    int m0 = blockIdx.x * 64;

#pragma unroll
    for (int i = 0; i < 8; i++) {
        int g = i * 256 + t;
        int row = g >> 5;
        int c8 = g & 31;
        int grow = m0 + row;
        if (grow >= NN) grow = NN - 1;
        uint4 v = *(const uint4*)(g1b + (size_t)grow * C1 + c8 * 8);
        int kc = c8 >> 2;
        int q = c8 & 3;
        Af[row >> 4][kc][q * 16 + (row & 15)] = v;
    }
    __syncthreads();

    int l = t & 63;
    int wv = t >> 6;

    bf16x8 a[8];
#pragma unroll
    for (int kc = 0; kc < 8; kc++) a[kc] = *(const bf16x8*)&Af[wv][kc][l];

    f32x4 acc[3];
#pragma unroll
    for (int tn = 0; tn < 3; tn++) acc[tn] = (f32x4){0.f, 0.f, 0.f, 0.f};

    const bf16x8* wb = (const bf16x8*)wB2 + l;
#pragma unroll
    for (int tn = 0; tn < 3; tn++) {
#pragma unroll
        for (int kc = 0; kc < 8; kc++) {
            bf16x8 b = wb[(tn * 8 + kc) * 64];
            acc[tn] = __builtin_amdgcn_mfma_f32_16x16x32_bf16(a[kc], b, acc[tn], 0, 0, 0);
        }
    }

    int q = l >> 4;
    int c = l & 15;
    int row0 = m0 + wv * 16 + q * 4;
    float ps[4] = {0.f, 0.f, 0.f, 0.f}, pd[4] = {0.f, 0.f, 0.f, 0.f};
#pragma unroll
    for (int tn = 0; tn < 3; tn++) {
        int col = tn * 16 + c;
        bool cok = col < CLS;
        float wsv = cok ? aws[col] : 0.f;
        float wdv = cok ? awd[col] : 0.f;
#pragma unroll
        for (int r = 0; r < 4; r++) {
            float v = acc[tn][r];
            int row = row0 + r;
            if (cok && row < NN) h2b[(size_t)row * CLS + col] = f2bf(v);
            ps[r] = fmaf(v, wsv, ps[r]);
            pd[r] = fmaf(v, wdv, pd[r]);
        }
    }
#pragma unroll
    for (int r = 0; r < 4; r++) {
        float a_ = ps[r], d_ = pd[r];
#pragma unroll
        for (int s = 1; s < 16; s <<= 1) {
            a_ += __shfl_xor(a_, s);
            d_ += __shfl_xor(d_, s);
        }
        int row = row0 + r;
        if (c == 0 && row < NN) {
            as2[row] = a_;
            ad2[row] = d_;
        }
    }
}

// ---------------- layer 2 aggregation + fused log_softmax ----------------
__global__ __launch_bounds__(256) void k_agg2(const unsigned short* __restrict__ h2b,
                                              const float* __restrict__ pw2,
                                              const int* __restrict__ offs,
                                              const int2* __restrict__ sedge,
                                              const float* __restrict__ b2,
                                              float* __restrict__ out) {
    int lane = threadIdx.x & 63;
    int half = lane >> 5;
    int hl = lane & 31;
    int cl = hl < 20 ? hl : 19;   // uint index within row (2 channels)
    int node = blockIdx.x * 4 + (threadIdx.x >> 6);
    int beg = offs[node];
    int end = (node + 1 < NN) ? offs[node + 1] : NE;
    float l = 0.f, aL = 0.f, aH = 0.f;
    const unsigned int* hv = (const unsigned int*)h2b;   // 20 uints per row

    if (beg < end) {
        int idx[4];
#pragma unroll
        for (int i = 0; i < 4; i++) idx[i] = sedge[beg + 2 * i + half].x;
        unsigned int hbA[2];
        float pA[2];
#pragma unroll
        for (int i = 0; i < 2; i++) {
            hbA[i] = hv[(size_t)idx[i] * 20 + cl];
            int e = beg + 2 * i + half;
            float p = pw2[e];
            pA[i] = (e < end) ? p : 0.f;
        }
        for (int j = beg; j < end; j += 8) {
            int idxN[4];
#pragma unroll
            for (int i = 0; i < 4; i++) idxN[i] = sedge[j + 8 + 2 * i + half].x;
            unsigned int hbB[2];
            float pB[2];
#pragma unroll
            for (int i = 0; i < 2; i++) {
                hbB[i] = hv[(size_t)idx[2 + i] * 20 + cl];
                int e = j + 4 + 2 * i + half;
                float p = pw2[e];
                pB[i] = (e < end) ? p : 0.f;
            }
#pragma unroll
            for (int i = 0; i < 2; i++) {
                float p = pA[i];
                l += p;
                aL = fmaf(p, bflo(hbA[i]), aL);
                aH = fmaf(p, bfhi(hbA[i]), aH);
            }
#pragma unroll
            for (int i = 0; i < 2; i++) {
                hbA[i] = hv[(size_t)idxN[i] * 20 + cl];
                int e = j + 8 + 2 * i + half;
                float p = pw2[e];
                pA[i] = (e < end) ? p : 0.f;
            }
#pragma unroll
            for (int i = 0; i < 2; i++) {
                float p = pB[i];
                l += p;
                aL = fmaf(p, bflo(hbB[i]), aL);
                aH = fmaf(p, bfhi(hbB[i]), aH);
            }
#pragma unroll
            for (int i = 0; i < 4; i++) idx[i] = idxN[i];
        }
    }
    l += __shfl_xor(l, 32);
    aL += __shfl_xor(aL, 32);
    aH += __shfl_xor(aH, 32);

    if (half == 0) {
        bool act = hl < 20;
        float inv = 1.f / (l + EPSF);
        float vL = -INFINITY, vH = -INFINITY;
        if (act) {
            float2 b = ((const float2*)b2)[cl];
            vL = aL * inv + b.x;
            vH = aH * inv + b.y;
        }
        float mx = fmaxf(vL, vH);
#pragma unroll
        for (int s = 16; s >= 1; s >>= 1) mx = fmaxf(mx, __shfl_xor(mx, s));
        float ex = act ? (__expf(vL - mx) + __expf(vH - mx)) : 0.f;
#pragma unroll
        for (int s = 16; s >= 1; s >>= 1) ex += __shfl_xor(ex, s);
        if (act) {
            float ls = __logf(ex);
            float2 o = {vL - mx - ls, vH - mx - ls};
            *(float2*)(out + (size_t)node * CLS + cl * 2) = o;
        }
    }
}

// ---------------- launch ----------------

extern "C" void kernel_launch(void* const* d_in, const int* in_sizes, int n_in,
                              void* d_out, int out_size, void* d_ws, size_t ws_size,
                              hipStream_t stream) {
    const float* x    = (const float*)d_in[0];
    const int*   ei   = (const int*)d_in[1];
    const float* W1   = (const float*)d_in[2];
    const float* as1w = (const float*)d_in[3];
    const float* ad1w = (const float*)d_in[4];
    const float* b1   = (const float*)d_in[5];
    const float* W2   = (const float*)d_in[6];
    const float* as2w = (const float*)d_in[7];
    const float* ad2w = (const float*)d_in[8];
    const float* b2   = (const float*)d_in[9];
    float* out = (float*)d_out;

    char* p = (char*)d_ws;
    auto alloc = [&](size_t bytes) {
        char* r = p;
        p += (bytes + 255) & ~(size_t)255;
        return r;
    };
    unsigned char* h1f8 = (unsigned char*)alloc((size_t)NN * C1);
    unsigned short* g1b = (unsigned short*)alloc((size_t)NN * C1 * 2);
    unsigned short* h2b = (unsigned short*)alloc((size_t)NN * CLS * 2);
    float* as1  = (float*)alloc((size_t)NN * 4 * 4);
    float* ad1  = (float*)alloc((size_t)NN * 4 * 4);
    float* as2  = (float*)alloc((size_t)NN * 4);
    float* ad2  = (float*)alloc((size_t)NN * 4);
    int* counts = (int*)alloc((size_t)NN * 4);
    int* offs   = (int*)alloc((size_t)NN * 4);
    int* cursor = (int*)alloc((size_t)NN * 4);
    int* parts  = (int*)alloc(64 * 4);
    int2* sedge = (int2*)alloc((size_t)(NE + 32) * 8);
    float4* pw1 = (float4*)alloc((size_t)(NE + 16) * 16);
    float* pw2  = (float*)alloc((size_t)(NE + 16) * 4);
    unsigned short* wB1 = (unsigned short*)alloc((size_t)4096 * 8 * 2);
    unsigned short* wB2 = (unsigned short*)alloc((size_t)1536 * 8 * 2);

    const int nb_scan = (NN + 1023) / 1024;  // 49
    const int nb_e = (NE + 255) / 256;       // 3125
    const int nb_ep = nb_e + 1;              // covers NE..NE+255 pad writers

    k_zero<<<(NN + 255) / 256, 256, 0, stream>>>(counts, NN);
    k_hist<<<nb_e, 256, 0, stream>>>(ei, counts);
    k_scan1<<<nb_scan, 1024, 0, stream>>>(counts, offs, parts);
    k_scan2<<<1, 64, 0, stream>>>(parts, nb_scan);
    k_scan3<<<(NN + 255) / 256, 256, 0, stream>>>(offs, parts, cursor);
    k_scatter<<<nb_e, 256, 0, stream>>>(ei, cursor, sedge);

    k_wconv<<<22, 256, 0, stream>>>(W1, W2, wB1, wB2);
    k_gemm1<<<(NN + 63) / 64, 256, 0, stream>>>(x, wB1, as1w, ad1w, h1f8, as1, ad1);
    k_ew1<<<nb_ep, 256, 0, stream>>>(sedge, as1, ad1, pw1);
    k_agg1<<<NN / 4, 256, 0, stream>>>(h1f8, (const float*)pw1, offs, sedge, b1, g1b);

    k_gemm2<<<(NN + 63) / 64, 256, 0, stream>>>(g1b, wB2, as2w, ad2w, h2b, as2, ad2);
    k_ew2<<<nb_ep, 256, 0, stream>>>(sedge, as2, ad2, pw2);
    k_agg2<<<NN / 4, 256, 0, stream>>>(h2b, pw2, offs, sedge, b2, out);
}